// Round 5
// baseline (286.591 us; speedup 1.0000x reference)
//
#include <hip/hip_runtime.h>
#include <cstdint>
#include <cstddef>

// Problem constants
#define B_  8192
#define T_  96
#define K_  32
#define H_  768
#define NK_ (T_ * K_)   // 3072

typedef __attribute__((ext_vector_type(8))) _Float16 f16x8;
typedef __attribute__((ext_vector_type(4))) float    f32x4;
typedef __attribute__((ext_vector_type(2))) float    f32x2;

#define SCALE_UP   4096.0f               // 2^12 on A and W each
#define SCALE_DOWN (1.0f / 16777216.0f)  // 2^-24

__device__ __forceinline__ void load_lds16(const void* g, void* l) {
    __builtin_amdgcn_global_load_lds(
        (const __attribute__((address_space(1))) unsigned int*)g,
        (__attribute__((address_space(3))) unsigned int*)l,
        16, 0, 0);
}

// Packed fp32 ops (VOP3P, full-rate on CDNA4). Note: no v_pk_max_f32 on CDNA —
// use fmaxf nests (compiler emits v_max3_f32) for Viterbi.
__device__ __forceinline__ f32x2 pk_add(f32x2 a, f32x2 b) {
    f32x2 d;
    asm("v_pk_add_f32 %0, %1, %2" : "=v"(d) : "v"(a), "v"(b));
    return d;
}
__device__ __forceinline__ f32x2 pk_fma(f32x2 a, f32x2 b, f32x2 c) {
    f32x2 d;
    asm("v_pk_fma_f32 %0, %1, %2, %3" : "=v"(d) : "v"(a), "v"(b), "v"(c));
    return d;
}

// ---------------------------------------------------------------------------
// Prepass A / Prepass W / GEMM: unchanged from R4 (known-good).
// ---------------------------------------------------------------------------
__global__ __launch_bounds__(256) void splitA_kernel(
    const float* __restrict__ A, _Float16* __restrict__ Ath, _Float16* __restrict__ Atl)
{
    const int g   = blockIdx.x * 256 + threadIdx.x;
    const int row = g / 96;
    const int o   = g - row * 96;
    const int ks  = o >> 2, qq = o & 3;
    const int r   = row & 127, rb = row >> 7;
    const size_t dst = (size_t)(rb * 24 + ks) * 4096 + r * 32 + ((qq ^ ((r >> 1) & 3)) << 3);

    f32x4 v0 = *(const f32x4*)(A + (size_t)row * H_ + o * 8);
    f32x4 v1 = *(const f32x4*)(A + (size_t)row * H_ + o * 8 + 4);
    f16x8 hi, lo;
#pragma unroll
    for (int e = 0; e < 8; e++) {
        float x = ((e < 4) ? v0[e] : v1[e - 4]) * SCALE_UP;
        _Float16 h = (_Float16)x;
        hi[e] = h;
        lo[e] = (_Float16)(x - (float)h);
    }
    *(f16x8*)&Ath[dst] = hi;
    *(f16x8*)&Atl[dst] = lo;
}

__global__ __launch_bounds__(256) void splitW_kernel(
    const float* __restrict__ W, _Float16* __restrict__ Wth, _Float16* __restrict__ Wtl)
{
    const int g   = blockIdx.x * 256 + threadIdx.x;
    const int ko  = g / NK_;
    const int col = g - ko * NK_;
    const int k0  = ko * 8;
    const int cb  = col >> 7, n = col & 127;
    const int ks  = k0 >> 5, qq = (k0 & 31) >> 3;
    const size_t dst = (size_t)(cb * 24 + ks) * 4096 + n * 32 + ((qq ^ ((n >> 1) & 3)) << 3);

    f16x8 hi, lo;
#pragma unroll
    for (int j = 0; j < 8; j++) {
        float x = W[(size_t)(k0 + j) * NK_ + col] * SCALE_UP;
        _Float16 h = (_Float16)x;
        hi[j] = h;
        lo[j] = (_Float16)(x - (float)h);
    }
    *(f16x8*)&Wth[dst] = hi;
    *(f16x8*)&Wtl[dst] = lo;
}

__global__ __launch_bounds__(256, 2) void gemm_mfma_sigmoid_kernel(
    const _Float16* __restrict__ Ath, const _Float16* __restrict__ Atl,
    const _Float16* __restrict__ Wth, const _Float16* __restrict__ Wtl,
    const float* __restrict__ bias, float* __restrict__ em)
{
    __shared__ _Float16 lds[2][4][4096];

    const int tid  = threadIdx.x;
    const int cb   = blockIdx.x;
    const int rb   = blockIdx.y;
    const int lane = tid & 63;
    const int w    = tid >> 6;
    const int wr   = w >> 1, wc = w & 1;
    const int fr   = lane & 15;
    const int kg   = lane >> 4;

    const _Float16* srcs[4] = {
        Ath + (size_t)(rb * 24) * 4096, Atl + (size_t)(rb * 24) * 4096,
        Wth + (size_t)(cb * 24) * 4096, Wtl + (size_t)(cb * 24) * 4096 };

    auto stage = [&](int ks, int bb) {
#pragma unroll
        for (int m = 0; m < 4; m++) {
            const _Float16* s = srcs[m] + (size_t)ks * 4096 + w * 1024 + lane * 8;
            _Float16* d = &lds[bb][m][w * 1024];
            load_lds16(s, d);
            load_lds16(s + 512, d + 512);
        }
    };

    f32x4 acc[4][4];
#pragma unroll
    for (int i = 0; i < 4; i++)
#pragma unroll
        for (int j = 0; j < 4; j++) acc[i][j] = (f32x4)0.0f;

    int cur = 0;
    stage(0, 0);

    for (int ks = 0; ks < 24; ks++) {
        __syncthreads();
        if (ks + 1 < 24) stage(ks + 1, cur ^ 1);

        f16x8 fah[4], fal[4], fbh[4], fbl[4];
#pragma unroll
        for (int mi = 0; mi < 4; mi++) {
            const int r   = wr * 64 + mi * 16 + fr;
            const int idx = r * 32 + ((kg ^ ((r >> 1) & 3)) << 3);
            fah[mi] = *(const f16x8*)&lds[cur][0][idx];
            fal[mi] = *(const f16x8*)&lds[cur][1][idx];
        }
#pragma unroll
        for (int ni = 0; ni < 4; ni++) {
            const int r   = wc * 64 + ni * 16 + fr;
            const int idx = r * 32 + ((kg ^ ((r >> 1) & 3)) << 3);
            fbh[ni] = *(const f16x8*)&lds[cur][2][idx];
            fbl[ni] = *(const f16x8*)&lds[cur][3][idx];
        }
#pragma unroll
        for (int mi = 0; mi < 4; mi++)
#pragma unroll
            for (int ni = 0; ni < 4; ni++) {
                acc[mi][ni] = __builtin_amdgcn_mfma_f32_16x16x32_f16(fah[mi], fbh[ni], acc[mi][ni], 0, 0, 0);
                acc[mi][ni] = __builtin_amdgcn_mfma_f32_16x16x32_f16(fah[mi], fbl[ni], acc[mi][ni], 0, 0, 0);
                acc[mi][ni] = __builtin_amdgcn_mfma_f32_16x16x32_f16(fal[mi], fbh[ni], acc[mi][ni], 0, 0, 0);
            }
        cur ^= 1;
    }

    const int er = rb * 128 + wr * 64 + (lane >> 4) * 4;
    const int ec = cb * 128 + wc * 64 + fr;
#pragma unroll
    for (int ni = 0; ni < 4; ni++) {
        const int   gc = ec + ni * 16;
        const float bv = bias[gc];
#pragma unroll
        for (int mi = 0; mi < 4; mi++)
#pragma unroll
            for (int r = 0; r < 4; r++) {
                const int gr = er + mi * 16 + r;
                float x = acc[mi][ni][r] * SCALE_DOWN + bv;
                em[(size_t)gr * NK_ + gc] = 1.0f / (1.0f + __expf(-x));
            }
    }
}

// ---------------------------------------------------------------------------
// CRF scan v3: 16-lane groups, 2 tag-columns per lane (l and l+16).
//  - forward in exp space: E state, 16 pk_fma/col; no per-step log/exp(beta)
//  - Viterbi value-only: pk_add + v_max3 nests; exact fp32 v-state row stored
//    to global (vhist) each step; backpointers recomputed in backtrace kernel
//  - renorm every 8 steps by exact power-of-2 (integer exponent accumulator)
// ---------------------------------------------------------------------------
__global__ __launch_bounds__(256) void crf_scan16_kernel(
    const float* __restrict__ em,       // [B_, NK_]
    const int* __restrict__ target,     // [B_, T_]
    const float* __restrict__ trans,    // [K_, K_]
    float2* __restrict__ vhist,         // [95][B_][16] float2 {v_l, v_l+16}
    float* __restrict__ out_tags,       // [B_, T_]: writes index 95 only
    float* __restrict__ ll)             // [B_]
{
    __shared__ float trans_s[K_ * K_];                    // 4 KB
    __shared__ __align__(16) float2 e2s[16][18];          // padded: stride 144B
    __shared__ __align__(16) float2 v2s[16][18];
    __shared__ unsigned char tgt_s[16][T_];               // 1.5 KB

    const int tid = threadIdx.x;
    const int g   = tid >> 4;      // group 0..15
    const int l   = tid & 15;      // lane-in-group; owns cols l and l+16
    const int b   = blockIdx.x * 16 + g;

    for (int i = tid; i < K_ * K_; i += 256) trans_s[i] = trans[i];
    __syncthreads();

    // constants: pair j covers prev-tags (j, j+16); cols a=l, b=l+16
    f32x2 t2a[16], t2b[16], E2a[16], E2b[16];
#pragma unroll
    for (int j = 0; j < 16; j++) {
        float a0 = trans_s[j * K_ + l];
        float a1 = trans_s[(j + 16) * K_ + l];
        float b0 = trans_s[j * K_ + (l + 16)];
        float b1 = trans_s[(j + 16) * K_ + (l + 16)];
        t2a[j] = (f32x2){a0, a1};  E2a[j] = (f32x2){__expf(a0), __expf(a1)};
        t2b[j] = (f32x2){b0, b1};  E2b[j] = (f32x2){__expf(b0), __expf(b1)};
    }

    const float* emb   = em + (size_t)b * NK_;
    float2*      vh_b  = vhist + (size_t)b * 16 + l;

    // ---- gold-path score: lane l covers t in {l, l+16, ..., l+80} ----
    int tg[6];
#pragma unroll
    for (int j = 0; j < 6; j++) {
        tg[j] = target[b * T_ + l + 16 * j];
        tgt_s[g][l + 16 * j] = (unsigned char)tg[j];
    }
    __builtin_amdgcn_wave_barrier();
    float gold = 0.0f;
#pragma unroll
    for (int j = 0; j < 6; j++) {
        const int t = l + 16 * j;
        gold += emb[t * K_ + tg[j]];
        if (t > 0) gold += trans_s[(int)tgt_s[g][t - 1] * K_ + tg[j]];
    }

    // ---- init (t=0): alpha_0 = em_0; E = exp(em_0) in (1,e) ----
    float em_a = emb[l];
    float em_b = emb[l + 16];
    float Ea = __expf(em_a), Eb = __expf(em_b);
    float va = em_a,         vb = em_b;
    int   expo_sum = 0;

    float na = emb[K_ + l];          // prefetch t=1
    float nb = emb[K_ + l + 16];

    auto STEP = [&](int t) {
        const float cem_a = na, cem_b = nb;          // em at time t
        na = emb[(t + 1) * K_ + l];                  // prefetch t+1 (t=95 safe: next row / vhist)
        nb = emb[(t + 1) * K_ + l + 16];

        vh_b[(size_t)(t - 1) * (B_ * 16)] = make_float2(va, vb);   // exact pre-step state

        e2s[g][l] = make_float2(Ea, Eb);
        v2s[g][l] = make_float2(va, vb);
        __builtin_amdgcn_wave_barrier();

        f32x2 aa0 = (f32x2){0.0f, 0.0f}, aa1 = aa0, ab0 = aa0, ab1 = aa0;
        float ma0 = -1e30f, ma1 = -1e30f, mb0 = -1e30f, mb1 = -1e30f;
#pragma unroll
        for (int j = 0; j < 8; j++) {
            f32x4 eq = *(const f32x4*)&e2s[g][2 * j];
            f32x4 vq = *(const f32x4*)&v2s[g][2 * j];
            f32x2 e0 = __builtin_shufflevector(eq, eq, 0, 1);
            f32x2 e1 = __builtin_shufflevector(eq, eq, 2, 3);
            f32x2 v0 = __builtin_shufflevector(vq, vq, 0, 1);
            f32x2 v1 = __builtin_shufflevector(vq, vq, 2, 3);
            aa0 = pk_fma(e0, E2a[2 * j], aa0);
            aa1 = pk_fma(e1, E2a[2 * j + 1], aa1);
            ab0 = pk_fma(e0, E2b[2 * j], ab0);
            ab1 = pk_fma(e1, E2b[2 * j + 1], ab1);
            f32x2 sa0 = pk_add(v0, t2a[2 * j]);
            f32x2 sa1 = pk_add(v1, t2a[2 * j + 1]);
            ma0 = fmaxf(fmaxf(ma0, sa0[0]), sa0[1]);   // v_max3
            ma1 = fmaxf(fmaxf(ma1, sa1[0]), sa1[1]);
            f32x2 sb0 = pk_add(v0, t2b[2 * j]);
            f32x2 sb1 = pk_add(v1, t2b[2 * j + 1]);
            mb0 = fmaxf(fmaxf(mb0, sb0[0]), sb0[1]);
            mb1 = fmaxf(fmaxf(mb1, sb1[0]), sb1[1]);
        }
        f32x2 sa = pk_add(aa0, aa1);
        f32x2 sb = pk_add(ab0, ab1);
        Ea = (sa[0] + sa[1]) * __expf(cem_a - 4.0f);
        Eb = (sb[0] + sb[1]) * __expf(cem_b - 4.0f);
        va = fmaxf(ma0, ma1) + cem_a;
        vb = fmaxf(mb0, mb1) + cem_b;
        __builtin_amdgcn_wave_barrier();   // reads done before next step's writes
    };

    auto RENORM = [&]() {
        float m = fmaxf(Ea, Eb);
#pragma unroll
        for (int d = 8; d >= 1; d >>= 1) m = fmaxf(m, __shfl_xor(m, d));
        const unsigned int ebits = (__float_as_uint(m) >> 23) & 255u;
        const float s = __uint_as_float((254u - ebits) << 23);   // exact 2^(127-ebits)
        Ea *= s; Eb *= s;
        expo_sum += (int)ebits - 127;
    };

    for (int tb = 1; tb <= 81; tb += 8) {
#pragma unroll
        for (int i = 0; i < 8; i++) STEP(tb + i);
        RENORM();
    }
#pragma unroll
    for (int i = 0; i < 7; i++) STEP(89 + i);   // t = 89..95

    // ---- final reductions over the 16-lane group ----
    float S = Ea + Eb;
#pragma unroll
    for (int d = 8; d >= 1; d >>= 1) S += __shfl_xor(S, d);
    const float logZ = __logf(S) + 380.0f + (float)expo_sum * 0.69314718055994531f;

    float gsum = gold;
#pragma unroll
    for (int d = 8; d >= 1; d >>= 1) gsum += __shfl_xor(gsum, d);

    float bv = va; int bi = l;
    if (vb > bv) { bv = vb; bi = l + 16; }
#pragma unroll
    for (int d = 8; d >= 1; d >>= 1) {
        float ov = __shfl_xor(bv, d);
        int   oi = __shfl_xor(bi, d);
        if (ov > bv || (ov == bv && oi < bi)) { bv = ov; bi = oi; }
    }

    if (l == 0) {
        ll[b] = gsum - logZ;
        out_tags[(size_t)b * T_ + (T_ - 1)] = (float)bi;
    }
}

// ---------------------------------------------------------------------------
// Backtrace: recompute argmax_p(v_t[p] + T[p][tag]) per step from stored v.
// 32-lane groups, 8 per block. v-row loads prefetched (address is tag-free).
// ---------------------------------------------------------------------------
__global__ __launch_bounds__(256) void crf_backtrace_kernel(
    const float2* __restrict__ vhist,   // [95][B_][16]
    const float* __restrict__ trans,    // [K_, K_]
    float* __restrict__ out_tags)       // [B_, T_]
{
    __shared__ float transT_s[K_ * K_];   // transT[c][p] = trans[p][c]

    const int tid = threadIdx.x;
    for (int i = tid; i < K_ * K_; i += 256) {
        const int c = i >> 5, p = i & 31;
        transT_s[i] = trans[p * K_ + c];
    }
    __syncthreads();

    const int g = tid >> 5;
    const int p = tid & 31;
    const int b = blockIdx.x * 8 + g;

    const float* vh = (const float*)vhist;   // flat floats
    float* ot = out_tags + (size_t)b * T_;

    int tag = (int)ot[T_ - 1];

    // lane p reads component (p>>4) of float2 index (p&15) of row (t,b)
    const size_t lane_off = (size_t)b * 32 + (p & 15) * 2 + (p >> 4);
    float cur = vh[(size_t)94 * (B_ * 32) + lane_off];

    for (int t = 94; t >= 0; t--) {
        float nxt = (t > 0) ? vh[(size_t)(t - 1) * (B_ * 32) + lane_off] : 0.0f;

        float bv = cur + transT_s[tag * K_ + p];
        int   bi = p;
#pragma unroll
        for (int d = 16; d >= 1; d >>= 1) {
            float ov = __shfl_xor(bv, d);
            int   oi = __shfl_xor(bi, d);
            if (ov > bv || (ov == bv && oi < bi)) { bv = ov; bi = oi; }
        }
        tag = bi;
        if (p == 0) ot[t] = (float)tag;
        cur = nxt;
    }
}

// ---------------------------------------------------------------------------
// Fallback CRF (R4, proven): used only if ws_size can't hold vhist.
// ---------------------------------------------------------------------------
__global__ __launch_bounds__(256) void crf_scan_fallback_kernel(
    const float* __restrict__ em, const int* __restrict__ target,
    const float* __restrict__ trans, float* __restrict__ out_tags,
    float* __restrict__ ll)
{
    __shared__ float  trans_s[K_ * K_];
    __shared__ float  e_s[8][K_];
    __shared__ float  v_s[8][K_];
    __shared__ unsigned int bp_s[8][24][K_];
    __shared__ unsigned char tgt_s[8][T_];

    const int tid = threadIdx.x;
    const int g   = tid >> 5;
    const int k   = tid & 31;
    const int b   = blockIdx.x * 8 + g;

    for (int i = tid; i < K_ * K_; i += 256) trans_s[i] = trans[i];
    __syncthreads();

    f32x2 t2[16], E2[16];
#pragma unroll
    for (int c = 0; c < 16; c++) {
        float a0 = trans_s[(2 * c) * K_ + k];
        float a1 = trans_s[(2 * c + 1) * K_ + k];
        t2[c] = (f32x2){a0, a1};
        E2[c] = (f32x2){__expf(a0), __expf(a1)};
    }

    const float* emb = em + (size_t)b * NK_ + k;

    const int tg0 = target[b * T_ + k];
    const int tg1 = target[b * T_ + 32 + k];
    const int tg2 = target[b * T_ + 64 + k];
    tgt_s[g][k] = (unsigned char)tg0;
    tgt_s[g][k + 32] = (unsigned char)tg1;
    tgt_s[g][k + 64] = (unsigned char)tg2;
    __builtin_amdgcn_wave_barrier();

    const float* emrow = em + (size_t)b * NK_;
    float sc = emrow[k * K_ + tg0] + emrow[(k + 32) * K_ + tg1] + emrow[(k + 64) * K_ + tg2];
    if (k > 0) sc += trans_s[(int)tgt_s[g][k - 1] * K_ + tg0];
    sc += trans_s[(int)tgt_s[g][k + 31] * K_ + tg1];
    sc += trans_s[(int)tgt_s[g][k + 63] * K_ + tg2];

    const float em0 = emb[0];
    float beta = em0;
    float v    = em0;
    float Cr   = 0.0f;
    unsigned int bpw = 0;
    float em_t = emb[1 * K_];

    auto STEP = [&](int t, int sh) {
        float em_n = emb[(t + 1) * K_];
        float e = __expf(beta);
        e_s[g][k] = e;
        v_s[g][k] = v;
        __builtin_amdgcn_wave_barrier();

        f32x2 acc = (f32x2){0.0f, 0.0f};
        float bv = -1e30f;
        int   bi = 0;
#pragma unroll
        for (int q = 0; q < 8; q++) {
            f32x4 eq = *(const f32x4*)&e_s[g][q * 4];
            f32x4 vq = *(const f32x4*)&v_s[g][q * 4];
            acc = pk_fma((f32x2){eq.x, eq.y}, E2[2 * q], acc);
            acc = pk_fma((f32x2){eq.z, eq.w}, E2[2 * q + 1], acc);
            f32x2 svA = pk_add((f32x2){vq.x, vq.y}, t2[2 * q]);
            f32x2 svB = pk_add((f32x2){vq.z, vq.w}, t2[2 * q + 1]);
            {
                float wv = (svA.y > svA.x) ? svA.y : svA.x;
                int   wi = (svA.y > svA.x) ? (4 * q + 1) : (4 * q);
                if (wv > bv) { bv = wv; bi = wi; }
            }
            {
                float wv = (svB.y > svB.x) ? svB.y : svB.x;
                int   wi = (svB.y > svB.x) ? (4 * q + 3) : (4 * q + 2);
                if (wv > bv) { bv = wv; bi = wi; }
            }
        }
        float sum = acc.x + acc.y;
        beta = __logf(sum) + (em_t - 4.0f);
        v    = bv + em_t;
        bpw |= (unsigned int)bi << (8 * sh);
        if (sh == 3) { bp_s[g][(t - 1) >> 2][k] = bpw; bpw = 0; }
        em_t = em_n;
    };

    for (int tb = 1; tb <= 89; tb += 4) {
        STEP(tb, 0); STEP(tb + 1, 1); STEP(tb + 2, 2); STEP(tb + 3, 3);
        if ((tb & 15) == 13) {
            float d = __shfl(beta, 0, 32);
            beta -= d;
            Cr += d;
        }
    }
    STEP(93, 0); STEP(94, 1); STEP(95, 2);
    bp_s[g][23][k] = bpw;
    __builtin_amdgcn_wave_barrier();

    float m2 = beta;
#pragma unroll
    for (int d = 16; d >= 1; d >>= 1) m2 = fmaxf(m2, __shfl_xor(m2, d));
    float s2 = __expf(beta - m2);
#pragma unroll
    for (int d = 16; d >= 1; d >>= 1) s2 += __shfl_xor(s2, d);
    const float logZ = 380.0f + Cr + m2 + __logf(s2);

    float scr = sc;
#pragma unroll
    for (int d = 16; d >= 1; d >>= 1) scr += __shfl_xor(scr, d);

    float bvv = v;
    int   bii = k;
#pragma unroll
    for (int d = 16; d >= 1; d >>= 1) {
        float ov = __shfl_xor(bvv, d);
        int   oi = __shfl_xor(bii, d);
        if (ov > bvv || (ov == bvv && oi < bii)) { bvv = ov; bii = oi; }
    }

    if (k == 0) {
        ll[b] = scr - logZ;
        float* ot = out_tags + (size_t)b * T_;
        int tag = bii;
        ot[T_ - 1] = (float)tag;
        for (int t = T_ - 2; t >= 0; t--) {
            unsigned int wd = bp_s[g][t >> 2][tag];
            tag = (wd >> (8 * (t & 3))) & 0xFF;
            ot[t] = (float)tag;
        }
    }
}

// ---------------------------------------------------------------------------
extern "C" void kernel_launch(void* const* d_in, const int* in_sizes, int n_in,
                              void* d_out, int out_size, void* d_ws, size_t ws_size,
                              hipStream_t stream)
{
    const float* hidden = (const float*)d_in[0];
    const int*   target = (const int*)d_in[1];
    const float* W      = (const float*)d_in[2];
    const float* bias   = (const float*)d_in[3];
    const float* trans  = (const float*)d_in[4];

    float* out      = (float*)d_out;
    float* out_tags = out;
    float* out_ll   = out + (size_t)B_ * T_;

    char* ws = (char*)d_ws;
    const size_t emB    = (size_t)B_ * NK_ * 4;              // 100.66 MB
    const size_t ahB    = (size_t)B_ * H_ * 2;               // 12.58 MB
    const size_t whB    = (size_t)H_ * NK_ * 2;              // 4.72 MB
    const size_t vhistB = (size_t)95 * B_ * 16 * 8;          // 99.61 MB

    float*    em  = (float*)ws;
    _Float16* Ath = (_Float16*)(ws + emB);                   // splits: dead after GEMM
    _Float16* Atl = (_Float16*)(ws + emB + ahB);
    _Float16* Wth = (_Float16*)(ws + emB + 2 * ahB);
    _Float16* Wtl = (_Float16*)(ws + emB + 2 * ahB + whB);
    float2*   vhist = (float2*)(ws + emB);                   // overlays splits (sequential use)

    splitA_kernel<<<(B_ * 96) / 256, 256, 0, stream>>>(hidden, Ath, Atl);
    splitW_kernel<<<(NK_ * 96) / 256, 256, 0, stream>>>(W, Wth, Wtl);

    dim3 gemm_grid(NK_ / 128, B_ / 128);
    gemm_mfma_sigmoid_kernel<<<gemm_grid, 256, 0, stream>>>(Ath, Atl, Wth, Wtl, bias, em);

    if (ws_size >= emB + vhistB) {
        crf_scan16_kernel<<<B_ / 16, 256, 0, stream>>>(em, target, trans, vhist, out_tags, out_ll);
        crf_backtrace_kernel<<<B_ / 8, 256, 0, stream>>>(vhist, trans, out_tags);
    } else {
        crf_scan_fallback_kernel<<<B_ / 8, 256, 0, stream>>>(em, target, trans, out_tags, out_ll);
    }
}

// Round 6
// 266.194 us; speedup vs baseline: 1.0766x; 1.0766x over previous
//
#include <hip/hip_runtime.h>
#include <cstdint>
#include <cstddef>

// Problem constants
#define B_  8192
#define T_  96
#define K_  32
#define H_  768
#define NK_ (T_ * K_)   // 3072

typedef __attribute__((ext_vector_type(8))) _Float16 f16x8;
typedef __attribute__((ext_vector_type(4))) float    f32x4;
typedef __attribute__((ext_vector_type(2))) float    f32x2;

#define SCALE_UP   4096.0f               // 2^12 on A and W each
#define SCALE_DOWN (1.0f / 16777216.0f)  // 2^-24

__device__ __forceinline__ void load_lds16(const void* g, void* l) {
    __builtin_amdgcn_global_load_lds(
        (const __attribute__((address_space(1))) unsigned int*)g,
        (__attribute__((address_space(3))) unsigned int*)l,
        16, 0, 0);
}

// Packed fp32 ops (VOP3P, full-rate on CDNA4).
__device__ __forceinline__ f32x2 pk_add(f32x2 a, f32x2 b) {
    f32x2 d;
    asm("v_pk_add_f32 %0, %1, %2" : "=v"(d) : "v"(a), "v"(b));
    return d;
}
__device__ __forceinline__ f32x2 pk_fma(f32x2 a, f32x2 b, f32x2 c) {
    f32x2 d;
    asm("v_pk_fma_f32 %0, %1, %2, %3" : "=v"(d) : "v"(a), "v"(b), "v"(c));
    return d;
}

// ---------------------------------------------------------------------------
// Prepass A / Prepass W / GEMM: unchanged (known-good since R3).
// ---------------------------------------------------------------------------
__global__ __launch_bounds__(256) void splitA_kernel(
    const float* __restrict__ A, _Float16* __restrict__ Ath, _Float16* __restrict__ Atl)
{
    const int g   = blockIdx.x * 256 + threadIdx.x;
    const int row = g / 96;
    const int o   = g - row * 96;
    const int ks  = o >> 2, qq = o & 3;
    const int r   = row & 127, rb = row >> 7;
    const size_t dst = (size_t)(rb * 24 + ks) * 4096 + r * 32 + ((qq ^ ((r >> 1) & 3)) << 3);

    f32x4 v0 = *(const f32x4*)(A + (size_t)row * H_ + o * 8);
    f32x4 v1 = *(const f32x4*)(A + (size_t)row * H_ + o * 8 + 4);
    f16x8 hi, lo;
#pragma unroll
    for (int e = 0; e < 8; e++) {
        float x = ((e < 4) ? v0[e] : v1[e - 4]) * SCALE_UP;
        _Float16 h = (_Float16)x;
        hi[e] = h;
        lo[e] = (_Float16)(x - (float)h);
    }
    *(f16x8*)&Ath[dst] = hi;
    *(f16x8*)&Atl[dst] = lo;
}

__global__ __launch_bounds__(256) void splitW_kernel(
    const float* __restrict__ W, _Float16* __restrict__ Wth, _Float16* __restrict__ Wtl)
{
    const int g   = blockIdx.x * 256 + threadIdx.x;
    const int ko  = g / NK_;
    const int col = g - ko * NK_;
    const int k0  = ko * 8;
    const int cb  = col >> 7, n = col & 127;
    const int ks  = k0 >> 5, qq = (k0 & 31) >> 3;
    const size_t dst = (size_t)(cb * 24 + ks) * 4096 + n * 32 + ((qq ^ ((n >> 1) & 3)) << 3);

    f16x8 hi, lo;
#pragma unroll
    for (int j = 0; j < 8; j++) {
        float x = W[(size_t)(k0 + j) * NK_ + col] * SCALE_UP;
        _Float16 h = (_Float16)x;
        hi[j] = h;
        lo[j] = (_Float16)(x - (float)h);
    }
    *(f16x8*)&Wth[dst] = hi;
    *(f16x8*)&Wtl[dst] = lo;
}

__global__ __launch_bounds__(256, 2) void gemm_mfma_sigmoid_kernel(
    const _Float16* __restrict__ Ath, const _Float16* __restrict__ Atl,
    const _Float16* __restrict__ Wth, const _Float16* __restrict__ Wtl,
    const float* __restrict__ bias, float* __restrict__ em)
{
    __shared__ _Float16 lds[2][4][4096];

    const int tid  = threadIdx.x;
    const int cb   = blockIdx.x;
    const int rb   = blockIdx.y;
    const int lane = tid & 63;
    const int w    = tid >> 6;
    const int wr   = w >> 1, wc = w & 1;
    const int fr   = lane & 15;
    const int kg   = lane >> 4;

    const _Float16* srcs[4] = {
        Ath + (size_t)(rb * 24) * 4096, Atl + (size_t)(rb * 24) * 4096,
        Wth + (size_t)(cb * 24) * 4096, Wtl + (size_t)(cb * 24) * 4096 };

    auto stage = [&](int ks, int bb) {
#pragma unroll
        for (int m = 0; m < 4; m++) {
            const _Float16* s = srcs[m] + (size_t)ks * 4096 + w * 1024 + lane * 8;
            _Float16* d = &lds[bb][m][w * 1024];
            load_lds16(s, d);
            load_lds16(s + 512, d + 512);
        }
    };

    f32x4 acc[4][4];
#pragma unroll
    for (int i = 0; i < 4; i++)
#pragma unroll
        for (int j = 0; j < 4; j++) acc[i][j] = (f32x4)0.0f;

    int cur = 0;
    stage(0, 0);

    for (int ks = 0; ks < 24; ks++) {
        __syncthreads();
        if (ks + 1 < 24) stage(ks + 1, cur ^ 1);

        f16x8 fah[4], fal[4], fbh[4], fbl[4];
#pragma unroll
        for (int mi = 0; mi < 4; mi++) {
            const int r   = wr * 64 + mi * 16 + fr;
            const int idx = r * 32 + ((kg ^ ((r >> 1) & 3)) << 3);
            fah[mi] = *(const f16x8*)&lds[cur][0][idx];
            fal[mi] = *(const f16x8*)&lds[cur][1][idx];
        }
#pragma unroll
        for (int ni = 0; ni < 4; ni++) {
            const int r   = wc * 64 + ni * 16 + fr;
            const int idx = r * 32 + ((kg ^ ((r >> 1) & 3)) << 3);
            fbh[ni] = *(const f16x8*)&lds[cur][2][idx];
            fbl[ni] = *(const f16x8*)&lds[cur][3][idx];
        }
#pragma unroll
        for (int mi = 0; mi < 4; mi++)
#pragma unroll
            for (int ni = 0; ni < 4; ni++) {
                acc[mi][ni] = __builtin_amdgcn_mfma_f32_16x16x32_f16(fah[mi], fbh[ni], acc[mi][ni], 0, 0, 0);
                acc[mi][ni] = __builtin_amdgcn_mfma_f32_16x16x32_f16(fah[mi], fbl[ni], acc[mi][ni], 0, 0, 0);
                acc[mi][ni] = __builtin_amdgcn_mfma_f32_16x16x32_f16(fal[mi], fbh[ni], acc[mi][ni], 0, 0, 0);
            }
        cur ^= 1;
    }

    const int er = rb * 128 + wr * 64 + (lane >> 4) * 4;
    const int ec = cb * 128 + wc * 64 + fr;
#pragma unroll
    for (int ni = 0; ni < 4; ni++) {
        const int   gc = ec + ni * 16;
        const float bv = bias[gc];
#pragma unroll
        for (int mi = 0; mi < 4; mi++)
#pragma unroll
            for (int r = 0; r < 4; r++) {
                const int gr = er + mi * 16 + r;
                float x = acc[mi][ni][r] * SCALE_DOWN + bv;
                em[(size_t)gr * NK_ + gc] = 1.0f / (1.0f + __expf(-x));
            }
    }
}

// ---------------------------------------------------------------------------
// CRF forward + in-scan backpointers + fused backtrace, v4.
//  - 16-lane groups, lane l owns tag-columns l and l+16 (halves DS per seq)
//  - forward in exp space (R5-proven math): pk_fma matvec, pow2 renorm/8 steps
//  - exchange arrays in per-tag order -> Viterbi candidates enumerate p=0..31
//    ascending; R4-proven pairwise merge keeps exact first-index tie-break
//  - bp packed 4/u32 in LDS (49 KB); lane-0 backtrace fused at the end
// ---------------------------------------------------------------------------
__global__ __launch_bounds__(256) void crf_scan16_kernel(
    const float* __restrict__ em,       // [B_, NK_]
    const int* __restrict__ target,     // [B_, T_]
    const float* __restrict__ trans,    // [K_, K_]
    float* __restrict__ out_tags,       // [B_, T_]
    float* __restrict__ ll)             // [B_]
{
    __shared__ float trans_s[K_ * K_];           // 4 KB
    __shared__ float es[16][40];                 // per-tag order, 160B row stride
    __shared__ float vs[16][40];
    __shared__ unsigned int bp_s[16][24][K_];    // 48 KB
    __shared__ unsigned char tgt_s[16][T_];      // 1.5 KB

    const int tid = threadIdx.x;
    const int g   = tid >> 4;      // group (sequence) 0..15
    const int l   = tid & 15;      // lane-in-group; owns cols l, l+16
    const int b   = blockIdx.x * 16 + g;

    for (int i = tid; i < K_ * K_; i += 256) trans_s[i] = trans[i];
    __syncthreads();

    // constants: pair c covers prev-tags (2c, 2c+1); col a = l, col b = l+16
    f32x2 t2a[16], t2b[16], E2a[16], E2b[16];
#pragma unroll
    for (int c = 0; c < 16; c++) {
        float a0 = trans_s[(2 * c) * K_ + l];
        float a1 = trans_s[(2 * c + 1) * K_ + l];
        float b0 = trans_s[(2 * c) * K_ + l + 16];
        float b1 = trans_s[(2 * c + 1) * K_ + l + 16];
        t2a[c] = (f32x2){a0, a1};  E2a[c] = (f32x2){__expf(a0), __expf(a1)};
        t2b[c] = (f32x2){b0, b1};  E2b[c] = (f32x2){__expf(b0), __expf(b1)};
    }

    const float* emb = em + (size_t)b * NK_;

    // ---- gold-path score (R5-proven): lane l covers t = l, l+16, ..., l+80 ----
    int tg[6];
#pragma unroll
    for (int j = 0; j < 6; j++) {
        tg[j] = target[b * T_ + l + 16 * j];
        tgt_s[g][l + 16 * j] = (unsigned char)tg[j];
    }
    __builtin_amdgcn_wave_barrier();
    float gold = 0.0f;
#pragma unroll
    for (int j = 0; j < 6; j++) {
        const int t = l + 16 * j;
        gold += emb[t * K_ + tg[j]];
        if (t > 0) gold += trans_s[(int)tgt_s[g][t - 1] * K_ + tg[j]];
    }

    // ---- init (t=0) ----
    const float em_a = emb[l];
    const float em_b = emb[l + 16];
    float Ea = __expf(em_a), Eb = __expf(em_b);
    float va = em_a,         vb = em_b;
    int   expo_sum = 0;
    unsigned int bpwa = 0, bpwb = 0;

    float na = emb[K_ + l];          // prefetch t=1
    float nb = emb[K_ + l + 16];

    auto STEP = [&](int t, int sh) {
        const float cem_a = na, cem_b = nb;          // em at time t
        na = emb[(t + 1) * K_ + l];                  // prefetch (t=95 reads into split
        nb = emb[(t + 1) * K_ + l + 16];             //  region of ws: allocated, unused)

        es[g][l] = Ea;  es[g][l + 16] = Eb;
        vs[g][l] = va;  vs[g][l + 16] = vb;
        __builtin_amdgcn_wave_barrier();

        f32x2 aa0 = (f32x2){0.0f, 0.0f}, aa1 = aa0, ab0 = aa0, ab1 = aa0;
        float bva = -1e30f, bvb = -1e30f;
        int   bia = 0, bib = 0;
#pragma unroll
        for (int j = 0; j < 8; j++) {
            f32x4 eq = *(const f32x4*)&es[g][4 * j];   // tags 4j..4j+3
            f32x4 vq = *(const f32x4*)&vs[g][4 * j];
            f32x2 e0 = (f32x2){eq[0], eq[1]};
            f32x2 e1 = (f32x2){eq[2], eq[3]};
            f32x2 v0 = (f32x2){vq[0], vq[1]};
            f32x2 v1 = (f32x2){vq[2], vq[3]};

            aa0 = pk_fma(e0, E2a[2 * j], aa0);
            aa1 = pk_fma(e1, E2a[2 * j + 1], aa1);
            ab0 = pk_fma(e0, E2b[2 * j], ab0);
            ab1 = pk_fma(e1, E2b[2 * j + 1], ab1);

            // Viterbi col a: candidates p = 4j..4j+3, ascending, first-tie wins
            {
                f32x2 s0 = pk_add(v0, t2a[2 * j]);
                f32x2 s1 = pk_add(v1, t2a[2 * j + 1]);
                float w0 = (s0[1] > s0[0]) ? s0[1] : s0[0];
                int   i0 = (s0[1] > s0[0]) ? (4 * j + 1) : (4 * j);
                float w1 = (s1[1] > s1[0]) ? s1[1] : s1[0];
                int   i1 = (s1[1] > s1[0]) ? (4 * j + 3) : (4 * j + 2);
                if (w1 > w0) { w0 = w1; i0 = i1; }
                if (w0 > bva) { bva = w0; bia = i0; }
            }
            // Viterbi col b
            {
                f32x2 s0 = pk_add(v0, t2b[2 * j]);
                f32x2 s1 = pk_add(v1, t2b[2 * j + 1]);
                float w0 = (s0[1] > s0[0]) ? s0[1] : s0[0];
                int   i0 = (s0[1] > s0[0]) ? (4 * j + 1) : (4 * j);
                float w1 = (s1[1] > s1[0]) ? s1[1] : s1[0];
                int   i1 = (s1[1] > s1[0]) ? (4 * j + 3) : (4 * j + 2);
                if (w1 > w0) { w0 = w1; i0 = i1; }
                if (w0 > bvb) { bvb = w0; bib = i0; }
            }
        }
        f32x2 sa = pk_add(aa0, aa1);
        f32x2 sb = pk_add(ab0, ab1);
        Ea = (sa[0] + sa[1]) * __expf(cem_a - 4.0f);
        Eb = (sb[0] + sb[1]) * __expf(cem_b - 4.0f);
        va = bva + cem_a;
        vb = bvb + cem_b;

        bpwa |= (unsigned int)bia << (8 * sh);
        bpwb |= (unsigned int)bib << (8 * sh);
        if (sh == 3) {
            bp_s[g][(t - 1) >> 2][l]      = bpwa;
            bp_s[g][(t - 1) >> 2][l + 16] = bpwb;
            bpwa = 0; bpwb = 0;
        }
        __builtin_amdgcn_wave_barrier();   // reads done before next step's writes
    };

    auto RENORM = [&]() {
        float m = fmaxf(Ea, Eb);
#pragma unroll
        for (int d = 8; d >= 1; d >>= 1) m = fmaxf(m, __shfl_xor(m, d));
        const unsigned int ebits = (__float_as_uint(m) >> 23) & 255u;
        const float s = __uint_as_float((254u - ebits) << 23);   // exact 2^(127-ebits)
        Ea *= s; Eb *= s;
        expo_sum += (int)ebits - 127;
    };

    for (int tb = 1; tb <= 89; tb += 4) {
        STEP(tb, 0); STEP(tb + 1, 1); STEP(tb + 2, 2); STEP(tb + 3, 3);
        if ((tb & 7) == 5) RENORM();       // after t = 8, 16, ..., 88
    }
    STEP(93, 0); STEP(94, 1); STEP(95, 2);
    bp_s[g][23][l]      = bpwa;            // bytes 0..2 of word 23 (t-1 = 92..94)
    bp_s[g][23][l + 16] = bpwb;
    __builtin_amdgcn_wave_barrier();

    // ---- final reductions over the 16-lane group ----
    float S = Ea + Eb;
#pragma unroll
    for (int d = 8; d >= 1; d >>= 1) S += __shfl_xor(S, d);
    const float logZ = __logf(S) + 380.0f + (float)expo_sum * 0.69314718055994531f;

    float gsum = gold;
#pragma unroll
    for (int d = 8; d >= 1; d >>= 1) gsum += __shfl_xor(gsum, d);

    float bv = va; int bi = l;
    if (vb > bv) { bv = vb; bi = l + 16; }
#pragma unroll
    for (int d = 8; d >= 1; d >>= 1) {
        float ov = __shfl_xor(bv, d);
        int   oi = __shfl_xor(bi, d);
        if (ov > bv || (ov == bv && oi < bi)) { bv = ov; bi = oi; }
    }

    if (l == 0) {
        ll[b] = gsum - logZ;
        float* ot = out_tags + (size_t)b * T_;
        int tag = bi;
        ot[T_ - 1] = (float)tag;
        for (int t = T_ - 2; t >= 0; t--) {
            unsigned int wd = bp_s[g][t >> 2][tag];
            tag = (wd >> (8 * (t & 3))) & 0xFF;
            ot[t] = (float)tag;
        }
    }
}

// ---------------------------------------------------------------------------
extern "C" void kernel_launch(void* const* d_in, const int* in_sizes, int n_in,
                              void* d_out, int out_size, void* d_ws, size_t ws_size,
                              hipStream_t stream)
{
    const float* hidden = (const float*)d_in[0];
    const int*   target = (const int*)d_in[1];
    const float* W      = (const float*)d_in[2];
    const float* bias   = (const float*)d_in[3];
    const float* trans  = (const float*)d_in[4];

    float* out      = (float*)d_out;
    float* out_tags = out;                    // B_*T_ tags (as f32)
    float* out_ll   = out + (size_t)B_ * T_;  // B_ log-likelihoods

    char* ws = (char*)d_ws;
    const size_t emB = (size_t)B_ * NK_ * 4;   // 100.66 MB
    const size_t ahB = (size_t)B_ * H_ * 2;    // 12.58 MB
    const size_t whB = (size_t)H_ * NK_ * 2;   // 4.72 MB

    float*    em  = (float*)ws;
    _Float16* Ath = (_Float16*)(ws + emB);
    _Float16* Atl = (_Float16*)(ws + emB + ahB);
    _Float16* Wth = (_Float16*)(ws + emB + 2 * ahB);
    _Float16* Wtl = (_Float16*)(ws + emB + 2 * ahB + whB);

    splitA_kernel<<<(B_ * 96) / 256, 256, 0, stream>>>(hidden, Ath, Atl);
    splitW_kernel<<<(NK_ * 96) / 256, 256, 0, stream>>>(W, Wth, Wtl);

    dim3 gemm_grid(NK_ / 128, B_ / 128);  // (24, 64)
    gemm_mfma_sigmoid_kernel<<<gemm_grid, 256, 0, stream>>>(Ath, Atl, Wth, Wtl, bias, em);

    crf_scan16_kernel<<<B_ / 16, 256, 0, stream>>>(em, target, trans, out_tags, out_ll);
}